// Round 4
// baseline (70.803 us; speedup 1.0000x reference)
//
#include <hip/hip_runtime.h>
#include <hip/hip_bf16.h>

// GNN layer: h1 = A @ x (fixed stencil), out = h1 @ W^T + bias
// x[64][65536] f32, W[256][65536] f32, bias[256], out[64][256] f32.
// GEMM in bf16 MFMA; split-K partials bf16; deterministic reduce.

#define MB     64
#define NOUT   256
#define KDIM   65536
#define KCHUNK 256
#define SK     (KDIM / KCHUNK)   // 256 split-K blocks

typedef __attribute__((ext_vector_type(8))) short bf16x8;
typedef __attribute__((ext_vector_type(4))) float f32x4;

__device__ __forceinline__ ushort f2bf(float f) {
    __hip_bfloat16 h = __float2bfloat16(f);
    return *reinterpret_cast<ushort*>(&h);
}

// ---------------------------------------------------------------------------
// Stencil -> bf16 h1.  h1[b,i] = x[b,i] + sum_o ([center(i)]+[center(i+o)])*x[b,i+o]
// centers = flat 257..65278; offsets flat with row wraparound (matches COO).
// ---------------------------------------------------------------------------
__global__ __launch_bounds__(256) void stencil_bf16(const float* __restrict__ x,
                                                    ushort* __restrict__ h1) {
    int g = (blockIdx.x * 256 + threadIdx.x) * 4;
    int i = g & (KDIM - 1);
    const float* xb = x + (g - i);
    const int offs[8] = {-1, 1, 256, -256, 255, 257, -257, -255};
    ushort4 ov;
    ushort* op = (ushort*)&ov;
    #pragma unroll
    for (int e = 0; e < 4; ++e) {
        int ii = i + e;
        float s = xb[ii];
        bool ci = (unsigned)(ii - 257) <= (65278u - 257u);
        #pragma unroll
        for (int t = 0; t < 8; ++t) {
            int j = ii + offs[t];
            bool cj = (unsigned)(j - 257) <= (65278u - 257u);
            float w = (ci ? 1.0f : 0.0f) + (cj ? 1.0f : 0.0f);
            if (w != 0.0f) s += w * xb[j];   // w>0 implies j in-bounds
        }
        op[e] = f2bf(s);
    }
    *(ushort4*)(h1 + g) = ov;
}

// ---------------------------------------------------------------------------
// Split-K MFMA GEMM, no LDS. Block kc handles k0..k0+255 for the FULL 64x256
// output. 16 waves; wave w owns n-tile w (16 cols), all 4 m-tiles.
// Fragments load straight from global: lane l -> row (l&15), k-8 group l>>4.
// W f32 -> bf16 in-register (v_cvt_pk). Partials bf16, layout [kc][n][m]
// so each lane stores 4 consecutive m as one 8B ushort4.
// ---------------------------------------------------------------------------
__global__ __launch_bounds__(1024, 4) void gemm_mfma(const ushort* __restrict__ h1,
                                                     const float* __restrict__ W,
                                                     ushort* __restrict__ part) {
    const int kc = blockIdx.x;
    const int w  = threadIdx.x >> 6;     // 0..15 = n-tile
    const int l  = threadIdx.x & 63;
    const int lr = l & 15;
    const int lg = l >> 4;
    const size_t kb = (size_t)kc * KCHUNK + lg * 8;

    f32x4 acc[4];
    #pragma unroll
    for (int a = 0; a < 4; ++a) acc[a] = (f32x4){0.f, 0.f, 0.f, 0.f};

    const ushort* ap = h1 + (size_t)lr * KDIM + kb;
    const float*  wp = W + (size_t)(w * 16 + lr) * KDIM + kb;

    #pragma unroll 2
    for (int ks = 0; ks < KCHUNK / 32; ++ks) {
        bf16x8 afrag[4];
        #pragma unroll
        for (int mt = 0; mt < 4; ++mt)
            afrag[mt] = *(const bf16x8*)(ap + (size_t)mt * 16 * KDIM + ks * 32);
        float4 w0 = *(const float4*)(wp + ks * 32);
        float4 w1 = *(const float4*)(wp + ks * 32 + 4);
        union { ushort u[8]; bf16x8 v; } bb;
        bb.u[0] = f2bf(w0.x); bb.u[1] = f2bf(w0.y);
        bb.u[2] = f2bf(w0.z); bb.u[3] = f2bf(w0.w);
        bb.u[4] = f2bf(w1.x); bb.u[5] = f2bf(w1.y);
        bb.u[6] = f2bf(w1.z); bb.u[7] = f2bf(w1.w);
        #pragma unroll
        for (int mt = 0; mt < 4; ++mt)
            acc[mt] = __builtin_amdgcn_mfma_f32_16x16x32_bf16(afrag[mt], bb.v,
                                                              acc[mt], 0, 0, 0);
    }

    // D layout: col(m-dir here) = lane&15 -> n; row = (lane>>4)*4 + reg -> m.
    // part[kc][n][m]: lane stores m = mt*16 + lg*4 + r, r=0..3 contiguous.
    ushort* pb = part + (size_t)kc * (MB * NOUT) + (size_t)(w * 16 + lr) * MB;
    #pragma unroll
    for (int mt = 0; mt < 4; ++mt) {
        ushort4 s;
        s.x = f2bf(acc[mt][0]); s.y = f2bf(acc[mt][1]);
        s.z = f2bf(acc[mt][2]); s.w = f2bf(acc[mt][3]);
        *(ushort4*)(pb + mt * 16 + lg * 4) = s;
    }
}

// ---------------------------------------------------------------------------
// Reduce 256 bf16 partials (+bias) -> f32 out[64][256].
// part[kc][n][m]; flat o = n*64+m; out[m][n]. 4 accumulators for ILP.
// ---------------------------------------------------------------------------
__global__ __launch_bounds__(256) void reduce_bf16(const ushort* __restrict__ part,
                                                   const float* __restrict__ bias,
                                                   float* __restrict__ out) {
    const int o = blockIdx.x * 256 + threadIdx.x;   // 0..16383
    float s0 = 0.f, s1 = 0.f, s2 = 0.f, s3 = 0.f;
    #pragma unroll 4
    for (int c = 0; c < SK; c += 4) {
        s0 += __uint_as_float((unsigned)part[(size_t)(c + 0) * (MB * NOUT) + o] << 16);
        s1 += __uint_as_float((unsigned)part[(size_t)(c + 1) * (MB * NOUT) + o] << 16);
        s2 += __uint_as_float((unsigned)part[(size_t)(c + 2) * (MB * NOUT) + o] << 16);
        s3 += __uint_as_float((unsigned)part[(size_t)(c + 3) * (MB * NOUT) + o] << 16);
    }
    const int n = o >> 6, m = o & 63;
    out[m * NOUT + n] = (s0 + s1) + (s2 + s3) + bias[n];
}

// ---------------------------------------------------------------------------
extern "C" void kernel_launch(void* const* d_in, const int* in_sizes, int n_in,
                              void* d_out, int out_size, void* d_ws, size_t ws_size,
                              hipStream_t stream) {
    const float* x    = (const float*)d_in[0];
    const float* W    = (const float*)d_in[1];
    const float* bias = (const float*)d_in[2];
    float* out = (float*)d_out;

    ushort* h1b  = (ushort*)d_ws;                    // 64*65536*2 = 8 MiB
    ushort* part = h1b + (size_t)MB * KDIM;          // 256*64*256*2 = 8 MiB

    stencil_bf16<<<(MB * KDIM) / 1024, 256, 0, stream>>>(x, h1b);
    gemm_mfma<<<SK, 1024, 0, stream>>>(h1b, W, part);
    reduce_bf16<<<(MB * NOUT) / 256, 256, 0, stream>>>(part, bias, out);
}

// Round 5
// 48.531 us; speedup vs baseline: 1.4589x; 1.4589x over previous
//
#include <hip/hip_runtime.h>
#include <hip/hip_bf16.h>

// GNN layer: h1 = A @ x (fixed stencil), out = h1 @ W^T + bias
// x[64][65536] f32, W[256][65536] f32, bias[256], out[64][256] f32.
// bf16 MFMA split-K GEMM; bf16 partials; deterministic reduce.

#define MB     64
#define NOUT   256
#define KDIM   65536
#define NTOT   (MB * KDIM)
#define KCHUNK 128
#define SKP    (KDIM / KCHUNK)   // 512 split-K chunks

typedef __attribute__((ext_vector_type(8))) short bf16x8;
typedef __attribute__((ext_vector_type(8))) unsigned short ushort8v;
typedef __attribute__((ext_vector_type(4))) float f32x4;

__device__ __forceinline__ ushort f2bf(float f) {
    __hip_bfloat16 h = __float2bfloat16(f);
    return *reinterpret_cast<ushort*>(&h);
}
__device__ __forceinline__ float bf2f(ushort u) {
    return __uint_as_float((unsigned)u << 16);
}

// ---------------------------------------------------------------------------
// Stencil -> bf16 h1. h1[b,i] = x[b,i] + sum_o ([center(i)]+[center(i+o)])*x[b,i+o]
// centers = flat 257..65278; offsets flat with row wraparound (matches COO).
// 8 elems/thread via 12 float4 loads; interior fast path (all weights = 2).
// Clamped OOB loads only feed weight-0 terms (proof: w>0 implies j in-row).
// ---------------------------------------------------------------------------
__global__ __launch_bounds__(256) void stencil_bf16(const float* __restrict__ x,
                                                    ushort* __restrict__ h1) {
    const int g  = (blockIdx.x * 256 + threadIdx.x) * 8;  // 8 elems
    const int i8 = g & (KDIM - 1);
    union Span { float4 v[4]; float f[16]; };
    Span u, c, d;
    #pragma unroll
    for (int q = 0; q < 4; ++q) {
        int bu = g - 260 + 4 * q; if (bu < 0) bu = 0;
        int bc = g - 4   + 4 * q; if (bc < 0) bc = 0; if (bc > NTOT - 4) bc = NTOT - 4;
        int bd = g + 252 + 4 * q; if (bd > NTOT - 4) bd = NTOT - 4;
        u.v[q] = *(const float4*)(x + bu);
        c.v[q] = *(const float4*)(x + bc);
        d.v[q] = *(const float4*)(x + bd);
    }
    ushort8v ov;
    if (i8 >= 520 && i8 <= 65008) {          // all 8 elems + neighbors interior
        #pragma unroll
        for (int e = 0; e < 8; ++e) {
            float nb = c.f[3 + e] + c.f[5 + e]
                     + u.f[3 + e] + u.f[4 + e] + u.f[5 + e]
                     + d.f[3 + e] + d.f[4 + e] + d.f[5 + e];
            ov[e] = (short)f2bf(fmaf(2.0f, nb, c.f[4 + e]));
        }
    } else {
        #pragma unroll
        for (int e = 0; e < 8; ++e) {
            const int ii = i8 + e;
            const float ci = ((unsigned)(ii - 257) <= (65278u - 257u)) ? 1.0f : 0.0f;
            float s = c.f[4 + e];
            const int   doff[8] = {-1, 1, -257, -256, -255, 255, 256, 257};
            const float* src[8] = {&c.f[3 + e], &c.f[5 + e],
                                   &u.f[3 + e], &u.f[4 + e], &u.f[5 + e],
                                   &d.f[3 + e], &d.f[4 + e], &d.f[5 + e]};
            #pragma unroll
            for (int t = 0; t < 8; ++t) {
                const int j = ii + doff[t];
                const float cj = ((unsigned)(j - 257) <= (65278u - 257u)) ? 1.0f : 0.0f;
                s = fmaf(ci + cj, *src[t], s);
            }
            ov[e] = (short)f2bf(s);
        }
    }
    *(ushort8v*)(h1 + g) = ov;
}

// ---------------------------------------------------------------------------
// Split-K MFMA GEMM, no LDS. Block kc: k0..k0+127 for the FULL 64x256 output.
// 16 waves; wave w owns n-tile w (16 cols). 2 blocks/CU -> 8 waves/SIMD.
// Full unroll: ~24 independent 16B loads in flight per wave.
// Partials bf16, [kc][n][m]; lane stores 4 consecutive m as one ushort4.
// ---------------------------------------------------------------------------
__global__ __launch_bounds__(1024, 4) void gemm_mfma(const ushort* __restrict__ h1,
                                                     const float* __restrict__ W,
                                                     ushort* __restrict__ part) {
    const int kc = blockIdx.x;
    const int w  = threadIdx.x >> 6;     // 0..15 = n-tile
    const int l  = threadIdx.x & 63;
    const int lr = l & 15;
    const int lg = l >> 4;
    const size_t kb = (size_t)kc * KCHUNK + lg * 8;

    f32x4 acc[4];
    #pragma unroll
    for (int a = 0; a < 4; ++a) acc[a] = (f32x4){0.f, 0.f, 0.f, 0.f};

    const ushort* ap = h1 + (size_t)lr * KDIM + kb;
    const float*  wp = W + (size_t)(w * 16 + lr) * KDIM + kb;

    #pragma unroll
    for (int ks = 0; ks < KCHUNK / 32; ++ks) {   // 4 fully-unrolled steps
        bf16x8 afrag[4];
        #pragma unroll
        for (int mt = 0; mt < 4; ++mt)
            afrag[mt] = *(const bf16x8*)(ap + (size_t)mt * 16 * KDIM + ks * 32);
        float4 w0 = *(const float4*)(wp + ks * 32);
        float4 w1 = *(const float4*)(wp + ks * 32 + 4);
        union { ushort u[8]; bf16x8 v; } bb;
        bb.u[0] = f2bf(w0.x); bb.u[1] = f2bf(w0.y);
        bb.u[2] = f2bf(w0.z); bb.u[3] = f2bf(w0.w);
        bb.u[4] = f2bf(w1.x); bb.u[5] = f2bf(w1.y);
        bb.u[6] = f2bf(w1.z); bb.u[7] = f2bf(w1.w);
        #pragma unroll
        for (int mt = 0; mt < 4; ++mt)
            acc[mt] = __builtin_amdgcn_mfma_f32_16x16x32_bf16(afrag[mt], bb.v,
                                                              acc[mt], 0, 0, 0);
    }

    // D layout: n = lane&15, m = (lane>>4)*4 + reg (m89/m91-verified).
    ushort* pb = part + (size_t)kc * (MB * NOUT) + (size_t)(w * 16 + lr) * MB;
    #pragma unroll
    for (int mt = 0; mt < 4; ++mt) {
        ushort4 s;
        s.x = f2bf(acc[mt][0]); s.y = f2bf(acc[mt][1]);
        s.z = f2bf(acc[mt][2]); s.w = f2bf(acc[mt][3]);
        *(ushort4*)(pb + mt * 16 + lg * 4) = s;
    }
}

// ---------------------------------------------------------------------------
// Reduce 512 bf16 partials (+bias) -> f32 out[64][256].
// 8 threads per output (64 chunks each, 4-acc ILP) + LDS combine. 512 blocks.
// ---------------------------------------------------------------------------
__global__ __launch_bounds__(256) void reduce_bf16(const ushort* __restrict__ part,
                                                   const float* __restrict__ bias,
                                                   float* __restrict__ out) {
    __shared__ float red[256];
    const int ol = threadIdx.x & 31;
    const int cg = threadIdx.x >> 5;               // 0..7
    const int o  = blockIdx.x * 32 + ol;           // 0..16383
    const ushort* p = part + (size_t)cg * 64 * (MB * NOUT) + o;
    float s0 = 0.f, s1 = 0.f, s2 = 0.f, s3 = 0.f;
    #pragma unroll 4
    for (int i = 0; i < 64; i += 4) {
        s0 += bf2f(p[(size_t)(i + 0) * (MB * NOUT)]);
        s1 += bf2f(p[(size_t)(i + 1) * (MB * NOUT)]);
        s2 += bf2f(p[(size_t)(i + 2) * (MB * NOUT)]);
        s3 += bf2f(p[(size_t)(i + 3) * (MB * NOUT)]);
    }
    red[threadIdx.x] = (s0 + s1) + (s2 + s3);
    __syncthreads();
    if (cg == 0) {
        float v = red[ol];
        #pragma unroll
        for (int jj = 1; jj < 8; ++jj) v += red[jj * 32 + ol];
        const int n = o >> 6, m = o & 63;
        out[m * NOUT + n] = v + bias[n];
    }
}

// ---------------------------------------------------------------------------
extern "C" void kernel_launch(void* const* d_in, const int* in_sizes, int n_in,
                              void* d_out, int out_size, void* d_ws, size_t ws_size,
                              hipStream_t stream) {
    const float* x    = (const float*)d_in[0];
    const float* W    = (const float*)d_in[1];
    const float* bias = (const float*)d_in[2];
    float* out = (float*)d_out;

    ushort* h1b  = (ushort*)d_ws;                    // 8 MiB
    ushort* part = h1b + (size_t)MB * KDIM;          // 512*16384*2 = 16 MiB

    stencil_bf16<<<NTOT / (256 * 8), 256, 0, stream>>>(x, h1b);
    gemm_mfma<<<SKP, 1024, 0, stream>>>(h1b, W, part);
    reduce_bf16<<<(MB * NOUT) / 32, 256, 0, stream>>>(part, bias, out);
}

// Round 6
// 42.111 us; speedup vs baseline: 1.6814x; 1.1525x over previous
//
#include <hip/hip_runtime.h>
#include <hip/hip_bf16.h>

// GNN layer: h1 = A @ x (fixed stencil), out = h1 @ W^T + bias
// x[64][65536] f32, W[256][65536] f32, bias[256], out[64][256] f32.
// bf16 MFMA GEMM; grid (n-tile, k-portion); in-block LDS combine -> f32
// partials [32][16384]; tiny deterministic reduce.

#define MB     64
#define NOUT   256
#define KDIM   65536
#define NTOT   (MB * KDIM)
#define KP     2048              // k per block
#define NKP    (KDIM / KP)       // 32 partial chunks
#define OTOT   (MB * NOUT)       // 16384

typedef __attribute__((ext_vector_type(8))) short bf16x8;
typedef __attribute__((ext_vector_type(8))) unsigned short ushort8v;
typedef __attribute__((ext_vector_type(4))) float f32x4;

__device__ __forceinline__ ushort f2bf(float f) {
    __hip_bfloat16 h = __float2bfloat16(f);
    return *reinterpret_cast<ushort*>(&h);
}

// ---------------------------------------------------------------------------
// Stencil -> bf16 h1. h1[b,i] = x[b,i] + sum_o ([center(i)]+[center(i+o)])*x[b,i+o]
// centers = flat 257..65278; offsets flat with row wraparound (matches COO).
// 8 elems/thread via 12 float4 loads; interior fast path (all weights = 2).
// Clamped OOB loads only feed weight-0 terms.
// ---------------------------------------------------------------------------
__global__ __launch_bounds__(256) void stencil_bf16(const float* __restrict__ x,
                                                    ushort* __restrict__ h1) {
    const int g  = (blockIdx.x * 256 + threadIdx.x) * 8;
    const int i8 = g & (KDIM - 1);
    union Span { float4 v[4]; float f[16]; };
    Span u, c, d;
    #pragma unroll
    for (int q = 0; q < 4; ++q) {
        int bu = g - 260 + 4 * q; if (bu < 0) bu = 0;
        int bc = g - 4   + 4 * q; if (bc < 0) bc = 0; if (bc > NTOT - 4) bc = NTOT - 4;
        int bd = g + 252 + 4 * q; if (bd > NTOT - 4) bd = NTOT - 4;
        u.v[q] = *(const float4*)(x + bu);
        c.v[q] = *(const float4*)(x + bc);
        d.v[q] = *(const float4*)(x + bd);
    }
    ushort8v ov;
    if (i8 >= 520 && i8 <= 65008) {
        #pragma unroll
        for (int e = 0; e < 8; ++e) {
            float nb = c.f[3 + e] + c.f[5 + e]
                     + u.f[3 + e] + u.f[4 + e] + u.f[5 + e]
                     + d.f[3 + e] + d.f[4 + e] + d.f[5 + e];
            ov[e] = (short)f2bf(fmaf(2.0f, nb, c.f[4 + e]));
        }
    } else {
        #pragma unroll
        for (int e = 0; e < 8; ++e) {
            const int ii = i8 + e;
            const float ci = ((unsigned)(ii - 257) <= (65278u - 257u)) ? 1.0f : 0.0f;
            float s = c.f[4 + e];
            const int   doff[8] = {-1, 1, -257, -256, -255, 255, 256, 257};
            const float* src[8] = {&c.f[3 + e], &c.f[5 + e],
                                   &u.f[3 + e], &u.f[4 + e], &u.f[5 + e],
                                   &d.f[3 + e], &d.f[4 + e], &d.f[5 + e]};
            #pragma unroll
            for (int t = 0; t < 8; ++t) {
                const int j = ii + doff[t];
                const float cj = ((unsigned)(j - 257) <= (65278u - 257u)) ? 1.0f : 0.0f;
                s = fmaf(ci + cj, *src[t], s);
            }
            ov[e] = (short)f2bf(s);
        }
    }
    *(ushort8v*)(h1 + g) = ov;
}

// ---------------------------------------------------------------------------
// MFMA GEMM. Block (nt, kp): n-tile nt (16 cols), k in [kp*2048, +2048).
// 16 waves split k 16 ways (128 k each; inner loop identical to R5).
// LDS combine of the 16 wave tiles -> one f32 partial [64 x 16] per block.
// part layout: [kp][m*256 + n]  (f32, 2 MiB total).
// ---------------------------------------------------------------------------
__global__ __launch_bounds__(1024, 4) void gemm_mfma(const ushort* __restrict__ h1,
                                                     const float* __restrict__ W,
                                                     float* __restrict__ part) {
    __shared__ float red[16 * 1024];     // 64 KiB
    const int nt = blockIdx.x;           // 0..15
    const int kp = blockIdx.y;           // 0..31
    const int wv = threadIdx.x >> 6;     // 0..15 (k-slice)
    const int l  = threadIdx.x & 63;
    const int lr = l & 15;
    const int lg = l >> 4;
    const size_t kb = (size_t)kp * KP + wv * 128 + lg * 8;

    f32x4 acc[4];
    #pragma unroll
    for (int a = 0; a < 4; ++a) acc[a] = (f32x4){0.f, 0.f, 0.f, 0.f};

    const ushort* ap = h1 + (size_t)lr * KDIM + kb;
    const float*  wp = W + (size_t)(nt * 16 + lr) * KDIM + kb;

    #pragma unroll
    for (int ks = 0; ks < 4; ++ks) {     // 4 fully-unrolled 32-k steps
        bf16x8 afrag[4];
        #pragma unroll
        for (int mt = 0; mt < 4; ++mt)
            afrag[mt] = *(const bf16x8*)(ap + (size_t)mt * 16 * KDIM + ks * 32);
        float4 w0 = *(const float4*)(wp + ks * 32);
        float4 w1 = *(const float4*)(wp + ks * 32 + 4);
        union { ushort u[8]; bf16x8 v; } bb;
        bb.u[0] = f2bf(w0.x); bb.u[1] = f2bf(w0.y);
        bb.u[2] = f2bf(w0.z); bb.u[3] = f2bf(w0.w);
        bb.u[4] = f2bf(w1.x); bb.u[5] = f2bf(w1.y);
        bb.u[6] = f2bf(w1.z); bb.u[7] = f2bf(w1.w);
        #pragma unroll
        for (int mt = 0; mt < 4; ++mt)
            acc[mt] = __builtin_amdgcn_mfma_f32_16x16x32_bf16(afrag[mt], bb.v,
                                                              acc[mt], 0, 0, 0);
    }

    // D layout: n-col = lane&15, m = (lane>>4)*4 + reg (m89/m91-verified).
    // red[wv][m*16 + ncol]
    #pragma unroll
    for (int mt = 0; mt < 4; ++mt)
        #pragma unroll
        for (int r = 0; r < 4; ++r)
            red[wv * 1024 + (mt * 16 + lg * 4 + r) * 16 + lr] = acc[mt][r];
    __syncthreads();

    // combine: thread t owns local output t = m*16 + ncol
    const int t = threadIdx.x;
    float s0 = 0.f, s1 = 0.f;
    #pragma unroll
    for (int j = 0; j < 16; j += 2) {
        s0 += red[j * 1024 + t];
        s1 += red[(j + 1) * 1024 + t];
    }
    part[(size_t)kp * OTOT + (t >> 4) * NOUT + nt * 16 + (t & 15)] = s0 + s1;
}

// ---------------------------------------------------------------------------
// Reduce 32 f32 partials (+bias) -> out[64][256].  512 blocks, 8 thr/output.
// ---------------------------------------------------------------------------
__global__ __launch_bounds__(256) void reduce_f32(const float* __restrict__ part,
                                                  const float* __restrict__ bias,
                                                  float* __restrict__ out) {
    __shared__ float red[256];
    const int ol = threadIdx.x & 31;
    const int cg = threadIdx.x >> 5;               // 0..7 -> 4 chunks each
    const int o  = blockIdx.x * 32 + ol;           // 0..16383
    const float* p = part + (size_t)cg * 4 * OTOT + o;
    red[threadIdx.x] = (p[0] + p[OTOT]) + (p[2 * OTOT] + p[3 * OTOT]);
    __syncthreads();
    if (cg == 0) {
        float v = red[ol];
        #pragma unroll
        for (int jj = 1; jj < 8; ++jj) v += red[jj * 32 + ol];
        out[o] = v + bias[o & (NOUT - 1)];
    }
}

// ---------------------------------------------------------------------------
extern "C" void kernel_launch(void* const* d_in, const int* in_sizes, int n_in,
                              void* d_out, int out_size, void* d_ws, size_t ws_size,
                              hipStream_t stream) {
    const float* x    = (const float*)d_in[0];
    const float* W    = (const float*)d_in[1];
    const float* bias = (const float*)d_in[2];
    float* out = (float*)d_out;

    ushort* h1b  = (ushort*)d_ws;                          // 8 MiB
    float*  part = (float*)((char*)d_ws + (size_t)MB * KDIM * 2);  // 2 MiB

    stencil_bf16<<<NTOT / (256 * 8), 256, 0, stream>>>(x, h1b);
    gemm_mfma<<<dim3(16, NKP), 1024, 0, stream>>>(h1b, W, part);
    reduce_f32<<<OTOT / 32, 256, 0, stream>>>(part, bias, out);
}

// Round 7
// 40.817 us; speedup vs baseline: 1.7346x; 1.0317x over previous
//
#include <hip/hip_runtime.h>
#include <hip/hip_bf16.h>

// GNN layer: h1 = A @ x (fixed stencil), out = h1 @ W^T + bias
// x[64][65536] f32, W[256][65536] f32, bias[256], out[64][256] f32.
// bf16 MFMA GEMM; grid (nt, kp) XCD-swizzled so all nt-blocks of a kp share
// one XCD's L2 for the h1 slice; in-block LDS combine -> f32 partials [32];
// tiny deterministic reduce.

#define MB     64
#define NOUT   256
#define KDIM   65536
#define NTOT   (MB * KDIM)
#define KP     2048              // k per block
#define NKP    (KDIM / KP)       // 32 partial chunks
#define OTOT   (MB * NOUT)       // 16384

typedef __attribute__((ext_vector_type(8))) short bf16x8;
typedef __attribute__((ext_vector_type(8))) unsigned short ushort8v;
typedef __attribute__((ext_vector_type(4))) float f32x4;

__device__ __forceinline__ ushort f2bf(float f) {
    __hip_bfloat16 h = __float2bfloat16(f);
    return *reinterpret_cast<ushort*>(&h);
}

// ---------------------------------------------------------------------------
// Stencil -> bf16 h1. h1[b,i] = x[b,i] + sum_o ([center(i)]+[center(i+o)])*x[b,i+o]
// centers = flat 257..65278; offsets flat with row wraparound (matches COO).
// 8 elems/thread via 12 float4 loads; interior fast path (all weights = 2).
// Clamped OOB loads only feed weight-0 terms.
// ---------------------------------------------------------------------------
__global__ __launch_bounds__(256) void stencil_bf16(const float* __restrict__ x,
                                                    ushort* __restrict__ h1) {
    const int g  = (blockIdx.x * 256 + threadIdx.x) * 8;
    const int i8 = g & (KDIM - 1);
    union Span { float4 v[4]; float f[16]; };
    Span u, c, d;
    #pragma unroll
    for (int q = 0; q < 4; ++q) {
        int bu = g - 260 + 4 * q; if (bu < 0) bu = 0;
        int bc = g - 4   + 4 * q; if (bc < 0) bc = 0; if (bc > NTOT - 4) bc = NTOT - 4;
        int bd = g + 252 + 4 * q; if (bd > NTOT - 4) bd = NTOT - 4;
        u.v[q] = *(const float4*)(x + bu);
        c.v[q] = *(const float4*)(x + bc);
        d.v[q] = *(const float4*)(x + bd);
    }
    ushort8v ov;
    if (i8 >= 520 && i8 <= 65008) {
        #pragma unroll
        for (int e = 0; e < 8; ++e) {
            float nb = c.f[3 + e] + c.f[5 + e]
                     + u.f[3 + e] + u.f[4 + e] + u.f[5 + e]
                     + d.f[3 + e] + d.f[4 + e] + d.f[5 + e];
            ov[e] = (short)f2bf(fmaf(2.0f, nb, c.f[4 + e]));
        }
    } else {
        #pragma unroll
        for (int e = 0; e < 8; ++e) {
            const int ii = i8 + e;
            const float ci = ((unsigned)(ii - 257) <= (65278u - 257u)) ? 1.0f : 0.0f;
            float s = c.f[4 + e];
            const int   doff[8] = {-1, 1, -257, -256, -255, 255, 256, 257};
            const float* src[8] = {&c.f[3 + e], &c.f[5 + e],
                                   &u.f[3 + e], &u.f[4 + e], &u.f[5 + e],
                                   &d.f[3 + e], &d.f[4 + e], &d.f[5 + e]};
            #pragma unroll
            for (int t = 0; t < 8; ++t) {
                const int j = ii + doff[t];
                const float cj = ((unsigned)(j - 257) <= (65278u - 257u)) ? 1.0f : 0.0f;
                s = fmaf(ci + cj, *src[t], s);
            }
            ov[e] = (short)f2bf(s);
        }
    }
    *(ushort8v*)(h1 + g) = ov;
}

// ---------------------------------------------------------------------------
// MFMA GEMM. Logical block (nt, kp): n-tile nt (16 cols), k in [kp*2048,+2048).
// Dispatch swizzle: d = (kp&7) + 8*(nt + 16*(kp>>3))  =>  d%8 == kp%8, so all
// 16 nt-blocks of a kp land on ONE XCD and share its L2 copy of the h1 slice.
// 16 waves split k 16 ways (128 k each). LDS combine -> f32 partial [64x16].
// part layout: [kp][m*256 + n]  (f32, 2 MiB total).
// ---------------------------------------------------------------------------
__global__ __launch_bounds__(1024, 4) void gemm_mfma(const ushort* __restrict__ h1,
                                                     const float* __restrict__ W,
                                                     float* __restrict__ part) {
    __shared__ float red[16 * 1024];     // 64 KiB
    const int d   = blockIdx.x;          // 0..511 (swizzled)
    const int xcd = d & 7;
    const int idx = d >> 3;              // 0..63
    const int nt  = idx & 15;
    const int kp  = xcd + 8 * (idx >> 4);
    const int wv = threadIdx.x >> 6;     // 0..15 (k-slice)
    const int l  = threadIdx.x & 63;
    const int lr = l & 15;
    const int lg = l >> 4;
    const size_t kb = (size_t)kp * KP + wv * 128 + lg * 8;

    f32x4 acc[4];
    #pragma unroll
    for (int a = 0; a < 4; ++a) acc[a] = (f32x4){0.f, 0.f, 0.f, 0.f};

    const ushort* ap = h1 + (size_t)lr * KDIM + kb;
    const float*  wp = W + (size_t)(nt * 16 + lr) * KDIM + kb;

    #pragma unroll
    for (int ks = 0; ks < 4; ++ks) {     // 4 fully-unrolled 32-k steps
        bf16x8 afrag[4];
        #pragma unroll
        for (int mt = 0; mt < 4; ++mt)
            afrag[mt] = *(const bf16x8*)(ap + (size_t)mt * 16 * KDIM + ks * 32);
        float4 w0 = *(const float4*)(wp + ks * 32);
        float4 w1 = *(const float4*)(wp + ks * 32 + 4);
        union { ushort u[8]; bf16x8 v; } bb;
        bb.u[0] = f2bf(w0.x); bb.u[1] = f2bf(w0.y);
        bb.u[2] = f2bf(w0.z); bb.u[3] = f2bf(w0.w);
        bb.u[4] = f2bf(w1.x); bb.u[5] = f2bf(w1.y);
        bb.u[6] = f2bf(w1.z); bb.u[7] = f2bf(w1.w);
        #pragma unroll
        for (int mt = 0; mt < 4; ++mt)
            acc[mt] = __builtin_amdgcn_mfma_f32_16x16x32_bf16(afrag[mt], bb.v,
                                                              acc[mt], 0, 0, 0);
    }

    // D layout: n-col = lane&15, m = (lane>>4)*4 + reg (m89/m91-verified).
    #pragma unroll
    for (int mt = 0; mt < 4; ++mt)
        #pragma unroll
        for (int r = 0; r < 4; ++r)
            red[wv * 1024 + (mt * 16 + lg * 4 + r) * 16 + lr] = acc[mt][r];
    __syncthreads();

    // combine: thread t owns local output t = m*16 + ncol
    const int t = threadIdx.x;
    float s0 = 0.f, s1 = 0.f;
    #pragma unroll
    for (int j = 0; j < 16; j += 2) {
        s0 += red[j * 1024 + t];
        s1 += red[(j + 1) * 1024 + t];
    }
    part[(size_t)kp * OTOT + (t >> 4) * NOUT + nt * 16 + (t & 15)] = s0 + s1;
}

// ---------------------------------------------------------------------------
// Reduce 32 f32 partials (+bias) -> out[64][256].  512 blocks, 8 thr/output.
// ---------------------------------------------------------------------------
__global__ __launch_bounds__(256) void reduce_f32(const float* __restrict__ part,
                                                  const float* __restrict__ bias,
                                                  float* __restrict__ out) {
    __shared__ float red[256];
    const int ol = threadIdx.x & 31;
    const int cg = threadIdx.x >> 5;               // 0..7 -> 4 chunks each
    const int o  = blockIdx.x * 32 + ol;           // 0..16383
    const float* p = part + (size_t)cg * 4 * OTOT + o;
    red[threadIdx.x] = (p[0] + p[OTOT]) + (p[2 * OTOT] + p[3 * OTOT]);
    __syncthreads();
    if (cg == 0) {
        float v = red[ol];
        #pragma unroll
        for (int jj = 1; jj < 8; ++jj) v += red[jj * 32 + ol];
        out[o] = v + bias[o & (NOUT - 1)];
    }
}

// ---------------------------------------------------------------------------
extern "C" void kernel_launch(void* const* d_in, const int* in_sizes, int n_in,
                              void* d_out, int out_size, void* d_ws, size_t ws_size,
                              hipStream_t stream) {
    const float* x    = (const float*)d_in[0];
    const float* W    = (const float*)d_in[1];
    const float* bias = (const float*)d_in[2];
    float* out = (float*)d_out;

    ushort* h1b  = (ushort*)d_ws;                          // 8 MiB
    float*  part = (float*)((char*)d_ws + (size_t)MB * KDIM * 2);  // 2 MiB

    stencil_bf16<<<NTOT / (256 * 8), 256, 0, stream>>>(x, h1b);
    gemm_mfma<<<16 * NKP, 1024, 0, stream>>>(h1b, W, part);
    reduce_f32<<<OTOT / 32, 256, 0, stream>>>(part, bias, out);
}